// Round 12
// baseline (158.323 us; speedup 1.0000x reference)
//
#include <hip/hip_runtime.h>

#define NNODES 200000
#define NQ     128
#define EPQ    1024
#define NE     (NQ*EPQ)
#define TOPK   128
#define NSEL   (NQ*TOPK)

// ---------------- helpers ----------------
__device__ __forceinline__ unsigned fkey(float f) {
  unsigned u = __float_as_uint(f);
  return (u & 0x80000000u) ? ~u : (u | 0x80000000u);
}
__device__ __forceinline__ float fdecode(unsigned k) {
  unsigned u = (k & 0x80000000u) ? (k ^ 0x80000000u) : ~k;
  return __uint_as_float(u);
}
__device__ __forceinline__ void fmarow(float* a, float x, const float4 n0, const float4 n1) {
  a[0] = fmaf(x, n0.x, a[0]); a[1] = fmaf(x, n0.y, a[1]);
  a[2] = fmaf(x, n0.z, a[2]); a[3] = fmaf(x, n0.w, a[3]);
  a[4] = fmaf(x, n1.x, a[4]); a[5] = fmaf(x, n1.y, a[5]);
  a[6] = fmaf(x, n1.z, a[6]); a[7] = fmaf(x, n1.w, a[7]);
}

typedef const __attribute__((address_space(1))) void* gas_ptr;
typedef __attribute__((address_space(3))) void* las_ptr;
__device__ __forceinline__ void gload16(const void* g, void* l) {
  __builtin_amdgcn_global_load_lds((gas_ptr)g, (las_ptr)l, 16, 0, 0);
}

// permuted within-row index for Nm (keeps each wave's 16B chunks contiguous)
__device__ __forceinline__ int nperm(int k) {
  const int q = k >> 2, p = k & 3;
  return (q & 1) * 64 + (q >> 1) * 4 + p;
}

#define NB_INIT 782   // ceil(200000/256)

// ---------------- fused setup: init tables + N matrix + per-query alpha/beta/c
__global__ __launch_bounds__(256) void k_setup(
    const float* __restrict__ Wq, const float* __restrict__ Wk,
    const float* __restrict__ qs_emb, const float* __restrict__ qr_emb,
    unsigned* __restrict__ segmax, float* __restrict__ segsum,
    int* __restrict__ flag, float* __restrict__ outs,
    float* __restrict__ Nm, float* __restrict__ alpha,
    float* __restrict__ beta, float* __restrict__ cv) {
  __shared__ float ph[128];
  __shared__ float sq[128];
  __shared__ float u[256], v[256];
  const int b = blockIdx.x, t = threadIdx.x;
  if (b < NB_INIT) {
    const int i = b * 256 + t;
    if (i < NNODES) { segmax[i] = 0u; segsum[i] = 0.f; flag[i] = 0; outs[i] = 0.f; }
    return;
  }
  if (b < NB_INIT + 128) {
    // N = WqL^T * WkL, row j, permuted layout
    const int j = b - NB_INIT;
    const int k = t & 127;
    const int ih = t >> 7;
    const int i0 = ih * 128;
    float a0 = 0.f, a1 = 0.f, a2 = 0.f, a3 = 0.f;
    for (int i = i0; i < i0 + 128; i += 4) {
      a0 = fmaf(Wq[(i + 0) * 256 + j], Wk[(i + 0) * 256 + k], a0);
      a1 = fmaf(Wq[(i + 1) * 256 + j], Wk[(i + 1) * 256 + k], a1);
      a2 = fmaf(Wq[(i + 2) * 256 + j], Wk[(i + 2) * 256 + k], a2);
      a3 = fmaf(Wq[(i + 3) * 256 + j], Wk[(i + 3) * 256 + k], a3);
    }
    const float p = (a0 + a1) + (a2 + a3);
    if (ih == 0) ph[k] = p;
    __syncthreads();
    if (ih == 1) Nm[j * 128 + nperm(k)] = ph[k] + p;
    return;
  }
  // per-query alpha/beta/c
  const int q = b - NB_INIT - 128;
  if (t < 64) sq[t] = qs_emb[q * 64 + t];
  else if (t < 128) sq[t] = qr_emb[q * 64 + (t - 64)];
  __syncthreads();
  {
    const float4* wq4 = (const float4*)(Wq + t * 256 + 128);
    const float4* wk4 = (const float4*)(Wk + t * 256 + 128);
    const float4* sq4 = (const float4*)sq;
    float uu = 0.f, vv = 0.f;
#pragma unroll 8
    for (int j = 0; j < 32; ++j) {
      const float4 a = wq4[j], bb = wk4[j], s = sq4[j];
      uu = fmaf(a.x, s.x, fmaf(a.y, s.y, fmaf(a.z, s.z, fmaf(a.w, s.w, uu))));
      vv = fmaf(bb.x, s.x, fmaf(bb.y, s.y, fmaf(bb.z, s.z, fmaf(bb.w, s.w, vv))));
    }
    u[t] = uu; v[t] = vv;
  }
  __syncthreads();
  if (t < 128) {
    float a0 = 0.f, a1 = 0.f, a2 = 0.f, a3 = 0.f;
    for (int i = 0; i < 256; i += 4) {
      a0 = fmaf(Wq[(i + 0) * 256 + t], v[i + 0], a0);
      a1 = fmaf(Wq[(i + 1) * 256 + t], v[i + 1], a1);
      a2 = fmaf(Wq[(i + 2) * 256 + t], v[i + 2], a2);
      a3 = fmaf(Wq[(i + 3) * 256 + t], v[i + 3], a3);
    }
    alpha[q * 128 + t] = (a0 + a1) + (a2 + a3);
  } else {
    const int k = t - 128;
    float b0 = 0.f, b1 = 0.f, b2 = 0.f, b3 = 0.f;
    for (int i = 0; i < 256; i += 4) {
      b0 = fmaf(u[i + 0], Wk[(i + 0) * 256 + k], b0);
      b1 = fmaf(u[i + 1], Wk[(i + 1) * 256 + k], b1);
      b2 = fmaf(u[i + 2], Wk[(i + 2) * 256 + k], b2);
      b3 = fmaf(u[i + 3], Wk[(i + 3) * 256 + k], b3);
    }
    beta[q * 128 + k] = (b0 + b1) + (b2 + b3);
  }
  __syncthreads();
  if (t < 64) {
    float c = u[t] * v[t] + u[t + 64] * v[t + 64] + u[t + 128] * v[t + 128] + u[t + 192] * v[t + 192];
    c += __shfl_xor(c, 32, 64);
    c += __shfl_xor(c, 16, 64);
    c += __shfl_xor(c, 8, 64);
    c += __shfl_xor(c, 4, 64);
    c += __shfl_xor(c, 2, 64);
    c += __shfl_xor(c, 1, 64);
    if (t == 0) cv[q] = c;
  }
}

// ---------------- edge logits: X from LDS, N from L2 (concurrent pipes) -------
// 256 edges/block, 512 threads, thread tile = 8 edges x 8 k.
// X tile (64KB) in LDS (two j-phases with restage); N read DIRECTLY from
// global (L2-resident 64KB, broadcast-coalesced: 256 unique B per wave load).
// Moving N off the LDS pipe halves LDS instructions; L2 reads overlap with
// LDS reads and FMA. LDS 69KB -> 2 blocks/CU. FMA order bit-identical.
__global__ __launch_bounds__(512, 1) void k_logits(
    const float* __restrict__ repr, const float* __restrict__ rel,
    const int* __restrict__ edges, const float* __restrict__ Nm,
    const float* __restrict__ alpha, const float* __restrict__ beta,
    const float* __restrict__ cv, float* __restrict__ logits,
    unsigned* __restrict__ segmax, int* __restrict__ csrc, int* __restrict__ cdst) {
  __shared__ float Xe[256 * 64];     // per-edge rows, chunk-swizzled (64KB)
  __shared__ float sA[128], sB[128];
  __shared__ int sSrc[256], sDst[256];
  const int t = threadIdx.x;
  const int e0 = blockIdx.x * 256;
  const int q = e0 >> 10;

  // tables + compact src/dst write-out
  if (t < 256) {
    const int src = edges[(size_t)(e0 + t) * 8 + 6];
    const int dst = edges[(size_t)(e0 + t) * 8 + 7];
    sSrc[t] = src; sDst[t] = dst;
    csrc[e0 + t] = src; cdst[e0 + t] = dst;
  } else if (t < 384) {
    sA[t - 256] = alpha[q * 128 + (t - 256)];
  } else {
    sB[t - 384] = beta[q * 128 + (t - 384)];
  }

  // stage phase-A X: repr[src] rows; lane (elr,c), el = r*32+elr.
  const int elr = t >> 4, c = t & 15;
  const int swzst = (elr >> 3) & 3;          // == (el>>3)&3 for all rounds
#pragma unroll
  for (int r = 0; r < 8; ++r) {
    const int el = r * 32 + elr;
    const int src = edges[(size_t)(e0 + el) * 8 + 6];
    const int cg = c ^ swzst;
    gload16((const char*)repr + ((size_t)src * 64 + cg * 4) * 4,
            (char*)Xe + ((size_t)el * 64 + c * 4) * 4);
  }
  __syncthreads();   // phase-A X + tables resident

  const int kg = t & 15, eg = t >> 4;        // 16 k-groups x 32 e-groups
  const int k0 = kg * 8, eb = eg * 8;
  const int kf = kg * 4;
  const int swz = eg & 3;
  float acc[8][8];
#pragma unroll
  for (int i = 0; i < 8; ++i)
#pragma unroll
    for (int m = 0; m < 8; ++m) acc[i][m] = 0.f;

  // ---- phase A: j = 0..63 (N streamed from L2) ----
#pragma unroll 2
  for (int J = 0; J < 16; ++J) {
    const float* __restrict__ Nr = Nm + (4 * J) * 128;
    float4 n0[4], n1[4];
#pragma unroll
    for (int jj = 0; jj < 4; ++jj) {
      n0[jj] = *(const float4*)(Nr + jj * 128 + kf);
      n1[jj] = *(const float4*)(Nr + jj * 128 + 64 + kf);
    }
    const int ch = (J ^ swz) * 4;
    float4 xv[8];
#pragma unroll
    for (int i = 0; i < 8; ++i)
      xv[i] = *(const float4*)(Xe + (eb + i) * 64 + ch);
#pragma unroll
    for (int jj = 0; jj < 4; ++jj) {
#pragma unroll
      for (int i = 0; i < 8; ++i) {
        const float xs = jj == 0 ? xv[i].x : jj == 1 ? xv[i].y : jj == 2 ? xv[i].z : xv[i].w;
        fmarow(acc[i], xs, n0[jj], n1[jj]);
      }
    }
  }
  __syncthreads();   // all phase-A reads of Xe done

  // restage Xe with rel rows
#pragma unroll
  for (int r = 0; r < 8; ++r) {
    const int el = r * 32 + elr;
    const int cg = c ^ swzst;
    gload16((const char*)rel + ((size_t)(e0 + el) * 64 + cg * 4) * 4,
            (char*)Xe + ((size_t)el * 64 + c * 4) * 4);
  }
  __syncthreads();   // phase-B X resident

  // ---- phase B: j = 64..127 ----
#pragma unroll 2
  for (int J = 0; J < 16; ++J) {
    const float* __restrict__ Nr = Nm + (64 + 4 * J) * 128;
    float4 n0[4], n1[4];
#pragma unroll
    for (int jj = 0; jj < 4; ++jj) {
      n0[jj] = *(const float4*)(Nr + jj * 128 + kf);
      n1[jj] = *(const float4*)(Nr + jj * 128 + 64 + kf);
    }
    const int ch = (J ^ swz) * 4;
    float4 xv[8];
#pragma unroll
    for (int i = 0; i < 8; ++i)
      xv[i] = *(const float4*)(Xe + (eb + i) * 64 + ch);
#pragma unroll
    for (int jj = 0; jj < 4; ++jj) {
#pragma unroll
      for (int i = 0; i < 8; ++i) {
        const float xs = jj == 0 ? xv[i].x : jj == 1 ? xv[i].y : jj == 2 ? xv[i].z : xv[i].w;
        fmarow(acc[i], xs, n0[jj], n1[jj]);
      }
    }
  }

  float aA[8], aB[8];
#pragma unroll
  for (int m = 0; m < 8; ++m) { aA[m] = sA[k0 + m]; aB[m] = sB[k0 + m]; }

  float part[8];
#pragma unroll
  for (int i = 0; i < 8; ++i) {
    const int el = eb + i;
    const int e = e0 + el;
    const float* xp;
    const float* yp;
    if (k0 < 64) {
      xp = repr + (size_t)sSrc[el] * 64 + k0;
      yp = repr + (size_t)sDst[el] * 64 + k0;
    } else {
      xp = rel + (size_t)e * 64 + (k0 - 64);
      yp = xp;
    }
    const float4 x0 = *(const float4*)xp;
    const float4 x1 = *(const float4*)(xp + 4);
    const float4 y0 = *(const float4*)yp;
    const float4 y1 = *(const float4*)(yp + 4);
    const float xs[8] = {x0.x, x0.y, x0.z, x0.w, x1.x, x1.y, x1.z, x1.w};
    const float ys[8] = {y0.x, y0.y, y0.z, y0.w, y1.x, y1.y, y1.z, y1.w};
    float p = 0.f;
#pragma unroll
    for (int m = 0; m < 8; ++m)
      p += (acc[i][m] + aB[m]) * ys[m] + aA[m] * xs[m];
    part[i] = p;
  }
#pragma unroll
  for (int i = 0; i < 8; ++i) {
    float p = part[i];
    p += __shfl_xor(p, 8, 64);
    p += __shfl_xor(p, 4, 64);
    p += __shfl_xor(p, 2, 64);
    p += __shfl_xor(p, 1, 64);
    part[i] = p;
  }
  if (kg == 0) {
    const float cq = cv[q];
    float lo[8];
#pragma unroll
    for (int i = 0; i < 8; ++i) lo[i] = part[i] + cq;
    float4 o0 = {lo[0], lo[1], lo[2], lo[3]};
    float4 o1 = {lo[4], lo[5], lo[6], lo[7]};
    *(float4*)(logits + e0 + eb) = o0;
    *(float4*)(logits + e0 + eb + 4) = o1;
    // fused segment-max
#pragma unroll
    for (int i = 0; i < 8; ++i)
      atomicMax(&segmax[sSrc[eb + i]], fkey(lo[i]));
  }
}

// ---------------- exp + segment sum (by src; uses compact src) ----------------
__global__ __launch_bounds__(256) void k_exsum(float* __restrict__ logits,
                                               const int* __restrict__ csrc,
                                               const unsigned* __restrict__ segmax,
                                               float* __restrict__ segsum) {
  const int e = blockIdx.x * 256 + threadIdx.x;
  const int src = csrc[e];
  const float m = fdecode(segmax[src]);
  const float ex = expf(logits[e] - m);
  logits[e] = ex;                       // in-place: now holds exp(l - m)
  atomicAdd(&segsum[src], ex);
}

// ---------------- per-query top-128: 4-pass radix select (exact tie-break) -----
__global__ __launch_bounds__(512) void k_topk(const float* __restrict__ ex,
                                              const float* __restrict__ segsum,
                                              const int* __restrict__ csrc,
                                              const int* __restrict__ cdst,
                                              const float* __restrict__ node_score,
                                              int* __restrict__ sel,
                                              int* __restrict__ flag,
                                              float* __restrict__ out_score,
                                              float* agg) {
  __shared__ unsigned keys[1024];
  __shared__ int hist[256];
  __shared__ int selEl[128];
  __shared__ int eqIdx[32];
  __shared__ int sB0, sRank, sCnt, sEq;
  const int q = blockIdx.x, t = threadIdx.x;
  for (int i = t; i < 1024; i += 512) {
    const int e = q * 1024 + i;
    const int src = csrc[e];
    const float ts = (ex[e] / segsum[src]) * node_score[src];
    keys[i] = fkey(ts);
  }
  unsigned prefix = 0, pmask = 0;
  int rank = 128;                 // rank-th largest among candidates
  __syncthreads();
#pragma unroll
  for (int pass = 0; pass < 4; ++pass) {
    const int shift = 24 - 8 * pass;
    if (t < 256) hist[t] = 0;
    __syncthreads();
    for (int i = t; i < 1024; i += 512) {
      const unsigned k = keys[i];
      if ((k & pmask) == prefix) atomicAdd(&hist[(k >> shift) & 255], 1);
    }
    __syncthreads();
    if (t < 64) {
      const int h0 = hist[4 * t], h1 = hist[4 * t + 1], h2 = hist[4 * t + 2], h3 = hist[4 * t + 3];
      const int s4 = h0 + h1 + h2 + h3;
      int S = s4;
      for (int d = 1; d < 64; d <<= 1) {
        const int o = __shfl_down(S, d, 64);
        if (t + d < 64) S += o;
      }
      const int Snext = S - s4;          // suffix sum excluding this lane's bins
      if (S >= rank && Snext < rank) {   // exactly one lane crosses
        int r = rank - Snext;            // r-th from top within these 4 bins
        int b;
        if (r <= h3) b = 3;
        else if (r <= h3 + h2) { b = 2; r -= h3; }
        else if (r <= h3 + h2 + h1) { b = 1; r -= h3 + h2; }
        else { b = 0; r -= h3 + h2 + h1; }
        sB0 = 4 * t + b; sRank = r;
      }
    }
    __syncthreads();
    prefix |= ((unsigned)sB0) << shift;
    pmask |= 0xFFu << shift;
    rank = sRank;
    __syncthreads();
  }
  const unsigned thr = prefix;           // 128th-largest key; take `rank` of == thr
  if (t == 0) { sCnt = 0; sEq = 0; }
  __syncthreads();
  for (int i = t; i < 1024; i += 512) {
    const unsigned k = keys[i];
    if (k > thr) { const int s = atomicAdd(&sCnt, 1); selEl[s] = i; }
    else if (k == thr) { const int j = atomicAdd(&sEq, 1); if (j < 32) eqIdx[j] = i; }
  }
  __syncthreads();
  if (t == 0) {
    int n = sEq; if (n > 32) n = 32;
    for (int a = 1; a < n; ++a) {        // ascending index sort (ties: smallest idx)
      const int v2 = eqIdx[a]; int b = a - 1;
      while (b >= 0 && eqIdx[b] > v2) { eqIdx[b + 1] = eqIdx[b]; --b; }
      eqIdx[b + 1] = v2;
    }
    for (int r2 = 0; r2 < rank; ++r2) selEl[sCnt + r2] = eqIdx[r2];
  }
  __syncthreads();
  if (t < 128) {
    const int el = selEl[t];
    const int e = q * 1024 + el;
    sel[q * 128 + t] = e;
    const int src = csrc[e];
    const int dst = cdst[e];
    const float soft = ex[e] / segsum[src];
    atomicAdd(&out_score[dst], soft * node_score[src]);
    flag[src] = 1;
  }
  __syncthreads();
  // zero agg rows for selected src (all zeroing precedes all adds: next kernel)
  for (int i = t; i < 128 * 64; i += 512) {
    const int s = i >> 6, d = i & 63;
    const int e = q * 1024 + selEl[s];
    const int src = csrc[e];
    agg[(size_t)src * 64 + d] = 0.f;
  }
}

// ---------------- scatter: agg[src] += soft * repr[dst] ----------------
__global__ __launch_bounds__(256) void k_scatter(const int* __restrict__ sel,
                                                 const int* __restrict__ csrc,
                                                 const int* __restrict__ cdst,
                                                 const float* __restrict__ ex,
                                                 const float* __restrict__ segsum,
                                                 const float* __restrict__ repr,
                                                 float* agg) {
  const int i = blockIdx.x * 4 + (threadIdx.x >> 6);   // selected slot
  const int d = threadIdx.x & 63;
  const int e = sel[i];
  const int src = csrc[e];
  const int dst = cdst[e];
  const float soft = ex[e] / segsum[src];
  atomicAdd(&agg[(size_t)src * 64 + d], soft * repr[(size_t)dst * 64 + d]);
}

// ---------------- final: out = leakyrelu(upd @ W_lin + b) ----------------
#define FN 192
__global__ __launch_bounds__(192) void k_final(const float* __restrict__ repr,
                                               const float* agg,      // aliases outr
                                               const int* __restrict__ flag,
                                               const float* __restrict__ Wl,
                                               const float* __restrict__ bl,
                                               float* outr) {
  __shared__ float Ut[64][FN];
  __shared__ float W[64][64];
  __shared__ float bs[64];
  const int t = threadIdx.x;
  const int n0blk = blockIdx.x * FN;
  for (int i = t; i < 4096; i += FN) W[i >> 6][i & 63] = Wl[i];
  if (t < 64) bs[t] = bl[t];
  {
    const int n = n0blk + t;
    const bool ok = n < NNODES;
    const float* rowp = repr;
    if (ok) rowp = (flag[n] ? agg : repr) + (size_t)n * 64;
#pragma unroll
    for (int i = 0; i < 16; ++i) {
      float4 v4 = ok ? ((const float4*)rowp)[i] : float4{0.f, 0.f, 0.f, 0.f};
      const int c = i * 4;
      Ut[c + 0][t] = v4.x; Ut[c + 1][t] = v4.y; Ut[c + 2][t] = v4.z; Ut[c + 3][t] = v4.w;
    }
  }
  __syncthreads();
  const int dg = t & 7, ng = t >> 3;       // 8 d-groups x 24 n-groups
  const int d0 = dg * 8, nb = ng * 8;
  float acc[8][8];
#pragma unroll
  for (int i = 0; i < 8; ++i)
#pragma unroll
    for (int m = 0; m < 8; ++m) acc[i][m] = 0.f;
#pragma unroll 2
  for (int c = 0; c < 64; ++c) {
    const float4 w0 = *(const float4*)&W[c][d0];
    const float4 w1 = *(const float4*)&W[c][d0 + 4];
    const float4 u0 = *(const float4*)&Ut[c][nb];
    const float4 u1 = *(const float4*)&Ut[c][nb + 4];
    fmarow(acc[0], u0.x, w0, w1);
    fmarow(acc[1], u0.y, w0, w1);
    fmarow(acc[2], u0.z, w0, w1);
    fmarow(acc[3], u0.w, w0, w1);
    fmarow(acc[4], u1.x, w0, w1);
    fmarow(acc[5], u1.y, w0, w1);
    fmarow(acc[6], u1.z, w0, w1);
    fmarow(acc[7], u1.w, w0, w1);
  }
  float bb[8];
#pragma unroll
  for (int m = 0; m < 8; ++m) bb[m] = bs[d0 + m];
#pragma unroll
  for (int i = 0; i < 8; ++i) {
    const int n = n0blk + nb + i;
    if (n < NNODES) {
      float o[8];
#pragma unroll
      for (int m = 0; m < 8; ++m) {
        float v = acc[i][m] + bb[m];
        o[m] = v > 0.f ? v : 0.01f * v;
      }
      float4 o0 = {o[0], o[1], o[2], o[3]};
      float4 o1 = {o[4], o[5], o[6], o[7]};
      *(float4*)(outr + (size_t)n * 64 + d0) = o0;
      *(float4*)(outr + (size_t)n * 64 + d0 + 4) = o1;
    }
  }
}

// ---------------- launcher ----------------
extern "C" void kernel_launch(void* const* d_in, const int* in_sizes, int n_in,
                              void* d_out, int out_size, void* d_ws, size_t ws_size,
                              hipStream_t stream) {
  const float* node_score = (const float*)d_in[0];
  const float* node_repr  = (const float*)d_in[1];
  const float* rel_emb    = (const float*)d_in[2];
  const float* qs_emb     = (const float*)d_in[3];
  const float* qr_emb     = (const float*)d_in[4];
  const float* Wq         = (const float*)d_in[5];
  const float* Wk         = (const float*)d_in[6];
  const float* Wl         = (const float*)d_in[7];
  const float* bl         = (const float*)d_in[8];
  const int*   edges      = (const int*)d_in[9];

  float* out_score = (float*)d_out;                 // [200000]
  float* out_repr  = out_score + NNODES;            // [200000 x 64]; doubles as agg

  float* ws = (float*)d_ws;
  size_t o = 0;
  float* Nm      = ws + o; o += 128 * 128;
  float* alpha   = ws + o; o += NQ * 128;
  float* beta    = ws + o; o += NQ * 128;
  float* cv      = ws + o; o += NQ;
  float* exl     = ws + o; o += NE;                 // logits, then exp(l-m)
  unsigned* segmax = (unsigned*)(ws + o); o += NNODES;
  float* segsum  = ws + o; o += NNODES;
  int* sel       = (int*)(ws + o); o += NSEL;
  int* flag      = (int*)(ws + o); o += NNODES;
  int* csrc      = (int*)(ws + o); o += NE;
  int* cdst      = (int*)(ws + o); o += NE;

  k_setup<<<NB_INIT + 256, 256, 0, stream>>>(Wq, Wk, qs_emb, qr_emb,
                                             segmax, segsum, flag, out_score,
                                             Nm, alpha, beta, cv);
  k_logits<<<NE / 256, 512, 0, stream>>>(node_repr, rel_emb, edges, Nm, alpha,
                                         beta, cv, exl, segmax, csrc, cdst);
  k_exsum<<<NE / 256, 256, 0, stream>>>(exl, csrc, segmax, segsum);
  k_topk<<<NQ, 512, 0, stream>>>(exl, segsum, csrc, cdst, node_score, sel, flag,
                                 out_score, out_repr);
  k_scatter<<<NSEL / 4, 256, 0, stream>>>(sel, csrc, cdst, exl, segsum,
                                          node_repr, out_repr);
  k_final<<<(NNODES + FN - 1) / FN, FN, 0, stream>>>(node_repr, out_repr, flag,
                                                     Wl, bl, out_repr);
}

// Round 13
// 152.012 us; speedup vs baseline: 1.0415x; 1.0415x over previous
//
#include <hip/hip_runtime.h>

#define NNODES 200000
#define NQ     128
#define EPQ    1024
#define NE     (NQ*EPQ)
#define TOPK   128
#define NSEL   (NQ*TOPK)

// ---------------- helpers ----------------
__device__ __forceinline__ unsigned fkey(float f) {
  unsigned u = __float_as_uint(f);
  return (u & 0x80000000u) ? ~u : (u | 0x80000000u);
}
__device__ __forceinline__ float fdecode(unsigned k) {
  unsigned u = (k & 0x80000000u) ? (k ^ 0x80000000u) : ~k;
  return __uint_as_float(u);
}
__device__ __forceinline__ void fmarow(float* a, float x, const float4 n0, const float4 n1) {
  a[0] = fmaf(x, n0.x, a[0]); a[1] = fmaf(x, n0.y, a[1]);
  a[2] = fmaf(x, n0.z, a[2]); a[3] = fmaf(x, n0.w, a[3]);
  a[4] = fmaf(x, n1.x, a[4]); a[5] = fmaf(x, n1.y, a[5]);
  a[6] = fmaf(x, n1.z, a[6]); a[7] = fmaf(x, n1.w, a[7]);
}

typedef const __attribute__((address_space(1))) void* gas_ptr;
typedef __attribute__((address_space(3))) void* las_ptr;
__device__ __forceinline__ void gload16(const void* g, void* l) {
  __builtin_amdgcn_global_load_lds((gas_ptr)g, (las_ptr)l, 16, 0, 0);
}

// permuted within-row index for Nm (conflict-free b128 N-row reads)
__device__ __forceinline__ int nperm(int k) {
  const int q = k >> 2, p = k & 3;
  return (q & 1) * 64 + (q >> 1) * 4 + p;
}

#define NB_INIT 782   // ceil(200000/256)

// ---------------- fused setup: init tables + N matrix + per-query alpha/beta/c
__global__ __launch_bounds__(256) void k_setup(
    const float* __restrict__ Wq, const float* __restrict__ Wk,
    const float* __restrict__ qs_emb, const float* __restrict__ qr_emb,
    unsigned* __restrict__ segmax, float* __restrict__ segsum,
    int* __restrict__ flag, float* __restrict__ outs,
    float* __restrict__ Nm, float* __restrict__ alpha,
    float* __restrict__ beta, float* __restrict__ cv) {
  __shared__ float ph[128];
  __shared__ float sq[128];
  __shared__ float u[256], v[256];
  const int b = blockIdx.x, t = threadIdx.x;
  if (b < NB_INIT) {
    const int i = b * 256 + t;
    if (i < NNODES) { segmax[i] = 0u; segsum[i] = 0.f; flag[i] = 0; outs[i] = 0.f; }
    return;
  }
  if (b < NB_INIT + 128) {
    // N = WqL^T * WkL, row j, permuted layout
    const int j = b - NB_INIT;
    const int k = t & 127;
    const int ih = t >> 7;
    const int i0 = ih * 128;
    float a0 = 0.f, a1 = 0.f, a2 = 0.f, a3 = 0.f;
    for (int i = i0; i < i0 + 128; i += 4) {
      a0 = fmaf(Wq[(i + 0) * 256 + j], Wk[(i + 0) * 256 + k], a0);
      a1 = fmaf(Wq[(i + 1) * 256 + j], Wk[(i + 1) * 256 + k], a1);
      a2 = fmaf(Wq[(i + 2) * 256 + j], Wk[(i + 2) * 256 + k], a2);
      a3 = fmaf(Wq[(i + 3) * 256 + j], Wk[(i + 3) * 256 + k], a3);
    }
    const float p = (a0 + a1) + (a2 + a3);
    if (ih == 0) ph[k] = p;
    __syncthreads();
    if (ih == 1) Nm[j * 128 + nperm(k)] = ph[k] + p;
    return;
  }
  // per-query alpha/beta/c
  const int q = b - NB_INIT - 128;
  if (t < 64) sq[t] = qs_emb[q * 64 + t];
  else if (t < 128) sq[t] = qr_emb[q * 64 + (t - 64)];
  __syncthreads();
  {
    const float4* wq4 = (const float4*)(Wq + t * 256 + 128);
    const float4* wk4 = (const float4*)(Wk + t * 256 + 128);
    const float4* sq4 = (const float4*)sq;
    float uu = 0.f, vv = 0.f;
#pragma unroll 8
    for (int j = 0; j < 32; ++j) {
      const float4 a = wq4[j], bb = wk4[j], s = sq4[j];
      uu = fmaf(a.x, s.x, fmaf(a.y, s.y, fmaf(a.z, s.z, fmaf(a.w, s.w, uu))));
      vv = fmaf(bb.x, s.x, fmaf(bb.y, s.y, fmaf(bb.z, s.z, fmaf(bb.w, s.w, vv))));
    }
    u[t] = uu; v[t] = vv;
  }
  __syncthreads();
  if (t < 128) {
    float a0 = 0.f, a1 = 0.f, a2 = 0.f, a3 = 0.f;
    for (int i = 0; i < 256; i += 4) {
      a0 = fmaf(Wq[(i + 0) * 256 + t], v[i + 0], a0);
      a1 = fmaf(Wq[(i + 1) * 256 + t], v[i + 1], a1);
      a2 = fmaf(Wq[(i + 2) * 256 + t], v[i + 2], a2);
      a3 = fmaf(Wq[(i + 3) * 256 + t], v[i + 3], a3);
    }
    alpha[q * 128 + t] = (a0 + a1) + (a2 + a3);
  } else {
    const int k = t - 128;
    float b0 = 0.f, b1 = 0.f, b2 = 0.f, b3 = 0.f;
    for (int i = 0; i < 256; i += 4) {
      b0 = fmaf(u[i + 0], Wk[(i + 0) * 256 + k], b0);
      b1 = fmaf(u[i + 1], Wk[(i + 1) * 256 + k], b1);
      b2 = fmaf(u[i + 2], Wk[(i + 2) * 256 + k], b2);
      b3 = fmaf(u[i + 3], Wk[(i + 3) * 256 + k], b3);
    }
    beta[q * 128 + k] = (b0 + b1) + (b2 + b3);
  }
  __syncthreads();
  if (t < 64) {
    float c = u[t] * v[t] + u[t + 64] * v[t + 64] + u[t + 128] * v[t + 128] + u[t + 192] * v[t + 192];
    c += __shfl_xor(c, 32, 64);
    c += __shfl_xor(c, 16, 64);
    c += __shfl_xor(c, 8, 64);
    c += __shfl_xor(c, 4, 64);
    c += __shfl_xor(c, 2, 64);
    c += __shfl_xor(c, 1, 64);
    if (t == 0) cv[q] = c;
  }
}

// ---------------- edge logits: 2 blocks/CU for cross-block pipe overlap -------
// 128 edges/block, 256 threads (4 waves), thread tile = 8 edges x 8 k.
// LDS ~66KB: half-N (Nh 32KB, restaged between phases) + Xe[128][64] (32KB)
// -> TWO blocks co-resident per CU; block A's FMA phase overlaps block B's
// LDS-read phase (independent convoys). Same tile/j-order as the 76us version
// -> bit-identical logits, ~112 VGPR (no spill).
__global__ __launch_bounds__(256, 2) void k_logits(
    const float* __restrict__ repr, const float* __restrict__ rel,
    const int* __restrict__ edges, const float* __restrict__ Nm,
    const float* __restrict__ alpha, const float* __restrict__ beta,
    const float* __restrict__ cv, float* __restrict__ logits,
    unsigned* __restrict__ segmax, int* __restrict__ csrc, int* __restrict__ cdst) {
  __shared__ float Nh[64 * 128];     // current 64-row half of permuted N (32KB)
  __shared__ float Xe[128 * 64];     // per-edge rows, chunk-swizzled (32KB)
  __shared__ float sA[128], sB[128];
  __shared__ int sSrc[128], sDst[128];
  const int t = threadIdx.x;
  const int e0 = blockIdx.x * 128;
  const int q = e0 >> 10;

  // stage N rows 0..63 (8 rounds x 256 lanes x 16B = 32KB)
  {
    const char* g = (const char*)Nm + (size_t)t * 16;
    char* l = (char*)Nh + (size_t)t * 16;
#pragma unroll
    for (int r = 0; r < 8; ++r) gload16(g + r * 4096, l + r * 4096);
  }

  // tables + compact src/dst write-out + alpha/beta slices
  if (t < 128) {
    const int src = edges[(size_t)(e0 + t) * 8 + 6];
    const int dst = edges[(size_t)(e0 + t) * 8 + 7];
    sSrc[t] = src; sDst[t] = dst;
    csrc[e0 + t] = src; cdst[e0 + t] = dst;
    sA[t] = alpha[q * 128 + t];
  } else {
    sB[t - 128] = beta[q * 128 + (t - 128)];
  }

  // stage phase-A X: repr[src] rows; lane (elr,c), el = r*16+elr (r 0..7).
  // LDS dest linear; global source chunk cg = c ^ ((el>>3)&3) (involution,
  // same key applied on the read side).
  const int elr = t >> 4, c = t & 15;
#pragma unroll
  for (int r = 0; r < 8; ++r) {
    const int el = r * 16 + elr;
    const int cg = c ^ ((el >> 3) & 3);
    const int src = edges[(size_t)(e0 + el) * 8 + 6];
    gload16((const char*)repr + ((size_t)src * 64 + cg * 4) * 4,
            (char*)Xe + ((size_t)el * 64 + c * 4) * 4);
  }
  __syncthreads();   // N-half + phase-A X + tables resident

  const int kg = t & 15, eg = t >> 4;        // 16 k-groups x 16 e-groups
  const int k0 = kg * 8, eb = eg * 8;
  const int kf = kg * 4;
  const int swz = eg & 3;
  float acc[8][8];
#pragma unroll
  for (int i = 0; i < 8; ++i)
#pragma unroll
    for (int m = 0; m < 8; ++m) acc[i][m] = 0.f;

  // ---- phase A: j = 0..63 ----
#pragma unroll 2
  for (int J = 0; J < 16; ++J) {
    const float* __restrict__ Nr = Nh + (4 * J) * 128;
    float4 n0[4], n1[4];
#pragma unroll
    for (int jj = 0; jj < 4; ++jj) {
      n0[jj] = *(const float4*)(Nr + jj * 128 + kf);
      n1[jj] = *(const float4*)(Nr + jj * 128 + 64 + kf);
    }
    const int ch = (J ^ swz) * 4;
    float4 xv[8];
#pragma unroll
    for (int i = 0; i < 8; ++i)
      xv[i] = *(const float4*)(Xe + (eb + i) * 64 + ch);
#pragma unroll
    for (int jj = 0; jj < 4; ++jj) {
#pragma unroll
      for (int i = 0; i < 8; ++i) {
        const float xs = jj == 0 ? xv[i].x : jj == 1 ? xv[i].y : jj == 2 ? xv[i].z : xv[i].w;
        fmarow(acc[i], xs, n0[jj], n1[jj]);
      }
    }
  }
  __syncthreads();   // all phase-A reads of Nh/Xe done

  // restage: Nh <- N rows 64..127, Xe <- rel rows
  {
    const char* g = (const char*)Nm + 32768 + (size_t)t * 16;
    char* l = (char*)Nh + (size_t)t * 16;
#pragma unroll
    for (int r = 0; r < 8; ++r) gload16(g + r * 4096, l + r * 4096);
  }
#pragma unroll
  for (int r = 0; r < 8; ++r) {
    const int el = r * 16 + elr;
    const int cg = c ^ ((el >> 3) & 3);
    gload16((const char*)rel + ((size_t)(e0 + el) * 64 + cg * 4) * 4,
            (char*)Xe + ((size_t)el * 64 + c * 4) * 4);
  }
  __syncthreads();   // phase-B N-half + X resident

  // ---- phase B: j = 64..127 ----
#pragma unroll 2
  for (int J = 0; J < 16; ++J) {
    const float* __restrict__ Nr = Nh + (4 * J) * 128;
    float4 n0[4], n1[4];
#pragma unroll
    for (int jj = 0; jj < 4; ++jj) {
      n0[jj] = *(const float4*)(Nr + jj * 128 + kf);
      n1[jj] = *(const float4*)(Nr + jj * 128 + 64 + kf);
    }
    const int ch = (J ^ swz) * 4;
    float4 xv[8];
#pragma unroll
    for (int i = 0; i < 8; ++i)
      xv[i] = *(const float4*)(Xe + (eb + i) * 64 + ch);
#pragma unroll
    for (int jj = 0; jj < 4; ++jj) {
#pragma unroll
      for (int i = 0; i < 8; ++i) {
        const float xs = jj == 0 ? xv[i].x : jj == 1 ? xv[i].y : jj == 2 ? xv[i].z : xv[i].w;
        fmarow(acc[i], xs, n0[jj], n1[jj]);
      }
    }
  }

  float aA[8], aB[8];
#pragma unroll
  for (int m = 0; m < 8; ++m) { aA[m] = sA[k0 + m]; aB[m] = sB[k0 + m]; }

  float part[8];
#pragma unroll
  for (int i = 0; i < 8; ++i) {
    const int el = eb + i;
    const int e = e0 + el;
    const float* xp;
    const float* yp;
    if (k0 < 64) {
      xp = repr + (size_t)sSrc[el] * 64 + k0;
      yp = repr + (size_t)sDst[el] * 64 + k0;
    } else {
      xp = rel + (size_t)e * 64 + (k0 - 64);
      yp = xp;
    }
    const float4 x0 = *(const float4*)xp;
    const float4 x1 = *(const float4*)(xp + 4);
    const float4 y0 = *(const float4*)yp;
    const float4 y1 = *(const float4*)(yp + 4);
    const float xs[8] = {x0.x, x0.y, x0.z, x0.w, x1.x, x1.y, x1.z, x1.w};
    const float ys[8] = {y0.x, y0.y, y0.z, y0.w, y1.x, y1.y, y1.z, y1.w};
    float p = 0.f;
#pragma unroll
    for (int m = 0; m < 8; ++m)
      p += (acc[i][m] + aB[m]) * ys[m] + aA[m] * xs[m];
    part[i] = p;
  }
#pragma unroll
  for (int i = 0; i < 8; ++i) {
    float p = part[i];
    p += __shfl_xor(p, 8, 64);
    p += __shfl_xor(p, 4, 64);
    p += __shfl_xor(p, 2, 64);
    p += __shfl_xor(p, 1, 64);
    part[i] = p;
  }
  if (kg == 0) {
    const float cq = cv[q];
    float lo[8];
#pragma unroll
    for (int i = 0; i < 8; ++i) lo[i] = part[i] + cq;
    float4 o0 = {lo[0], lo[1], lo[2], lo[3]};
    float4 o1 = {lo[4], lo[5], lo[6], lo[7]};
    *(float4*)(logits + e0 + eb) = o0;
    *(float4*)(logits + e0 + eb + 4) = o1;
    // fused segment-max
#pragma unroll
    for (int i = 0; i < 8; ++i)
      atomicMax(&segmax[sSrc[eb + i]], fkey(lo[i]));
  }
}

// ---------------- exp + segment sum (by src; uses compact src) ----------------
__global__ __launch_bounds__(256) void k_exsum(float* __restrict__ logits,
                                               const int* __restrict__ csrc,
                                               const unsigned* __restrict__ segmax,
                                               float* __restrict__ segsum) {
  const int e = blockIdx.x * 256 + threadIdx.x;
  const int src = csrc[e];
  const float m = fdecode(segmax[src]);
  const float ex = expf(logits[e] - m);
  logits[e] = ex;                       // in-place: now holds exp(l - m)
  atomicAdd(&segsum[src], ex);
}

// ---------------- per-query top-128: 4-pass radix select (exact tie-break) -----
__global__ __launch_bounds__(512) void k_topk(const float* __restrict__ ex,
                                              const float* __restrict__ segsum,
                                              const int* __restrict__ csrc,
                                              const int* __restrict__ cdst,
                                              const float* __restrict__ node_score,
                                              int* __restrict__ sel,
                                              int* __restrict__ flag,
                                              float* __restrict__ out_score,
                                              float* agg) {
  __shared__ unsigned keys[1024];
  __shared__ int hist[256];
  __shared__ int selEl[128];
  __shared__ int eqIdx[32];
  __shared__ int sB0, sRank, sCnt, sEq;
  const int q = blockIdx.x, t = threadIdx.x;
  for (int i = t; i < 1024; i += 512) {
    const int e = q * 1024 + i;
    const int src = csrc[e];
    const float ts = (ex[e] / segsum[src]) * node_score[src];
    keys[i] = fkey(ts);
  }
  unsigned prefix = 0, pmask = 0;
  int rank = 128;                 // rank-th largest among candidates
  __syncthreads();
#pragma unroll
  for (int pass = 0; pass < 4; ++pass) {
    const int shift = 24 - 8 * pass;
    if (t < 256) hist[t] = 0;
    __syncthreads();
    for (int i = t; i < 1024; i += 512) {
      const unsigned k = keys[i];
      if ((k & pmask) == prefix) atomicAdd(&hist[(k >> shift) & 255], 1);
    }
    __syncthreads();
    if (t < 64) {
      const int h0 = hist[4 * t], h1 = hist[4 * t + 1], h2 = hist[4 * t + 2], h3 = hist[4 * t + 3];
      const int s4 = h0 + h1 + h2 + h3;
      int S = s4;
      for (int d = 1; d < 64; d <<= 1) {
        const int o = __shfl_down(S, d, 64);
        if (t + d < 64) S += o;
      }
      const int Snext = S - s4;          // suffix sum excluding this lane's bins
      if (S >= rank && Snext < rank) {   // exactly one lane crosses
        int r = rank - Snext;            // r-th from top within these 4 bins
        int b;
        if (r <= h3) b = 3;
        else if (r <= h3 + h2) { b = 2; r -= h3; }
        else if (r <= h3 + h2 + h1) { b = 1; r -= h3 + h2; }
        else { b = 0; r -= h3 + h2 + h1; }
        sB0 = 4 * t + b; sRank = r;
      }
    }
    __syncthreads();
    prefix |= ((unsigned)sB0) << shift;
    pmask |= 0xFFu << shift;
    rank = sRank;
    __syncthreads();
  }
  const unsigned thr = prefix;           // 128th-largest key; take `rank` of == thr
  if (t == 0) { sCnt = 0; sEq = 0; }
  __syncthreads();
  for (int i = t; i < 1024; i += 512) {
    const unsigned k = keys[i];
    if (k > thr) { const int s = atomicAdd(&sCnt, 1); selEl[s] = i; }
    else if (k == thr) { const int j = atomicAdd(&sEq, 1); if (j < 32) eqIdx[j] = i; }
  }
  __syncthreads();
  if (t == 0) {
    int n = sEq; if (n > 32) n = 32;
    for (int a = 1; a < n; ++a) {        // ascending index sort (ties: smallest idx)
      const int v2 = eqIdx[a]; int b = a - 1;
      while (b >= 0 && eqIdx[b] > v2) { eqIdx[b + 1] = eqIdx[b]; --b; }
      eqIdx[b + 1] = v2;
    }
    for (int r2 = 0; r2 < rank; ++r2) selEl[sCnt + r2] = eqIdx[r2];
  }
  __syncthreads();
  if (t < 128) {
    const int el = selEl[t];
    const int e = q * 1024 + el;
    sel[q * 128 + t] = e;
    const int src = csrc[e];
    const int dst = cdst[e];
    const float soft = ex[e] / segsum[src];
    atomicAdd(&out_score[dst], soft * node_score[src]);
    flag[src] = 1;
  }
  __syncthreads();
  // zero agg rows for selected src (all zeroing precedes all adds: next kernel)
  for (int i = t; i < 128 * 64; i += 512) {
    const int s = i >> 6, d = i & 63;
    const int e = q * 1024 + selEl[s];
    const int src = csrc[e];
    agg[(size_t)src * 64 + d] = 0.f;
  }
}

// ---------------- scatter: agg[src] += soft * repr[dst] ----------------
__global__ __launch_bounds__(256) void k_scatter(const int* __restrict__ sel,
                                                 const int* __restrict__ csrc,
                                                 const int* __restrict__ cdst,
                                                 const float* __restrict__ ex,
                                                 const float* __restrict__ segsum,
                                                 const float* __restrict__ repr,
                                                 float* agg) {
  const int i = blockIdx.x * 4 + (threadIdx.x >> 6);   // selected slot
  const int d = threadIdx.x & 63;
  const int e = sel[i];
  const int src = csrc[e];
  const int dst = cdst[e];
  const float soft = ex[e] / segsum[src];
  atomicAdd(&agg[(size_t)src * 64 + d], soft * repr[(size_t)dst * 64 + d]);
}

// ---------------- final: out = leakyrelu(upd @ W_lin + b) ----------------
#define FN 192
__global__ __launch_bounds__(192) void k_final(const float* __restrict__ repr,
                                               const float* agg,      // aliases outr
                                               const int* __restrict__ flag,
                                               const float* __restrict__ Wl,
                                               const float* __restrict__ bl,
                                               float* outr) {
  __shared__ float Ut[64][FN];
  __shared__ float W[64][64];
  __shared__ float bs[64];
  const int t = threadIdx.x;
  const int n0blk = blockIdx.x * FN;
  for (int i = t; i < 4096; i += FN) W[i >> 6][i & 63] = Wl[i];
  if (t < 64) bs[t] = bl[t];
  {
    const int n = n0blk + t;
    const bool ok = n < NNODES;
    const float* rowp = repr;
    if (ok) rowp = (flag[n] ? agg : repr) + (size_t)n * 64;
#pragma unroll
    for (int i = 0; i < 16; ++i) {
      float4 v4 = ok ? ((const float4*)rowp)[i] : float4{0.f, 0.f, 0.f, 0.f};
      const int c = i * 4;
      Ut[c + 0][t] = v4.x; Ut[c + 1][t] = v4.y; Ut[c + 2][t] = v4.z; Ut[c + 3][t] = v4.w;
    }
  }
  __syncthreads();
  const int dg = t & 7, ng = t >> 3;       // 8 d-groups x 24 n-groups
  const int d0 = dg * 8, nb = ng * 8;
  float acc[8][8];
#pragma unroll
  for (int i = 0; i < 8; ++i)
#pragma unroll
    for (int m = 0; m < 8; ++m) acc[i][m] = 0.f;
#pragma unroll 2
  for (int c = 0; c < 64; ++c) {
    const float4 w0 = *(const float4*)&W[c][d0];
    const float4 w1 = *(const float4*)&W[c][d0 + 4];
    const float4 u0 = *(const float4*)&Ut[c][nb];
    const float4 u1 = *(const float4*)&Ut[c][nb + 4];
    fmarow(acc[0], u0.x, w0, w1);
    fmarow(acc[1], u0.y, w0, w1);
    fmarow(acc[2], u0.z, w0, w1);
    fmarow(acc[3], u0.w, w0, w1);
    fmarow(acc[4], u1.x, w0, w1);
    fmarow(acc[5], u1.y, w0, w1);
    fmarow(acc[6], u1.z, w0, w1);
    fmarow(acc[7], u1.w, w0, w1);
  }
  float bb[8];
#pragma unroll
  for (int m = 0; m < 8; ++m) bb[m] = bs[d0 + m];
#pragma unroll
  for (int i = 0; i < 8; ++i) {
    const int n = n0blk + nb + i;
    if (n < NNODES) {
      float o[8];
#pragma unroll
      for (int m = 0; m < 8; ++m) {
        float v = acc[i][m] + bb[m];
        o[m] = v > 0.f ? v : 0.01f * v;
      }
      float4 o0 = {o[0], o[1], o[2], o[3]};
      float4 o1 = {o[4], o[5], o[6], o[7]};
      *(float4*)(outr + (size_t)n * 64 + d0) = o0;
      *(float4*)(outr + (size_t)n * 64 + d0 + 4) = o1;
    }
  }
}

// ---------------- launcher ----------------
extern "C" void kernel_launch(void* const* d_in, const int* in_sizes, int n_in,
                              void* d_out, int out_size, void* d_ws, size_t ws_size,
                              hipStream_t stream) {
  const float* node_score = (const float*)d_in[0];
  const float* node_repr  = (const float*)d_in[1];
  const float* rel_emb    = (const float*)d_in[2];
  const float* qs_emb     = (const float*)d_in[3];
  const float* qr_emb     = (const float*)d_in[4];
  const float* Wq         = (const float*)d_in[5];
  const float* Wk         = (const float*)d_in[6];
  const float* Wl         = (const float*)d_in[7];
  const float* bl         = (const float*)d_in[8];
  const int*   edges      = (const int*)d_in[9];

  float* out_score = (float*)d_out;                 // [200000]
  float* out_repr  = out_score + NNODES;            // [200000 x 64]; doubles as agg

  float* ws = (float*)d_ws;
  size_t o = 0;
  float* Nm      = ws + o; o += 128 * 128;
  float* alpha   = ws + o; o += NQ * 128;
  float* beta    = ws + o; o += NQ * 128;
  float* cv      = ws + o; o += NQ;
  float* exl     = ws + o; o += NE;                 // logits, then exp(l-m)
  unsigned* segmax = (unsigned*)(ws + o); o += NNODES;
  float* segsum  = ws + o; o += NNODES;
  int* sel       = (int*)(ws + o); o += NSEL;
  int* flag      = (int*)(ws + o); o += NNODES;
  int* csrc      = (int*)(ws + o); o += NE;
  int* cdst      = (int*)(ws + o); o += NE;

  k_setup<<<NB_INIT + 256, 256, 0, stream>>>(Wq, Wk, qs_emb, qr_emb,
                                             segmax, segsum, flag, out_score,
                                             Nm, alpha, beta, cv);
  k_logits<<<NE / 128, 256, 0, stream>>>(node_repr, rel_emb, edges, Nm, alpha,
                                         beta, cv, exl, segmax, csrc, cdst);
  k_exsum<<<NE / 256, 256, 0, stream>>>(exl, csrc, segmax, segsum);
  k_topk<<<NQ, 512, 0, stream>>>(exl, segsum, csrc, cdst, node_score, sel, flag,
                                 out_score, out_repr);
  k_scatter<<<NSEL / 4, 256, 0, stream>>>(sel, csrc, cdst, exl, segsum,
                                          node_repr, out_repr);
  k_final<<<(NNODES + FN - 1) / FN, FN, 0, stream>>>(node_repr, out_repr, flag,
                                                     Wl, bl, out_repr);
}